// Round 7
// baseline (3217.437 us; speedup 1.0000x reference)
//
#include <hip/hip_runtime.h>
#include <math.h>
#include <float.h>

#define N_EVENTS 4096
#define TS 1024
#define NN 64
#define BLK 512          // events per sequential block
#define NBLK (N_EVENTS / BLK)

typedef int v2i __attribute__((ext_vector_type(2)));

// ---- DPP permute ----
template<int CTRL>
__device__ __forceinline__ float dppmov(float x) {
    return __int_as_float(__builtin_amdgcn_mov_dpp(__float_as_int(x), CTRL, 0xF, 0xF, true));
}
// 0xB1 quad xor1, 0x4E quad xor2, 0x141 row_half_mirror, 0x140 row_mirror

// ---- gfx950 permlane swaps (self-swap helpers for full-wave reduce) ----
#if __has_builtin(__builtin_amdgcn_permlane16_swap) && __has_builtin(__builtin_amdgcn_permlane32_swap)
__device__ __forceinline__ void sswap16(float x, float& a, float& b) {
    v2i r = __builtin_amdgcn_permlane16_swap(__float_as_int(x), __float_as_int(x), false, false);
    a = __int_as_float(r[0]); b = __int_as_float(r[1]);
}
__device__ __forceinline__ void sswap32(float x, float& a, float& b) {
    v2i r = __builtin_amdgcn_permlane32_swap(__float_as_int(x), __float_as_int(x), false, false);
    a = __int_as_float(r[0]); b = __int_as_float(r[1]);
}
#else
__device__ __forceinline__ void sswap16(float x, float& a, float& b) {
    asm("v_mov_b32 %0, %2\n\tv_mov_b32 %1, %2\n\ts_nop 1\n\tv_permlane16_swap_b32 %0, %1"
        : "=&v"(a), "=&v"(b) : "v"(x));
}
__device__ __forceinline__ void sswap32(float x, float& a, float& b) {
    asm("v_mov_b32 %0, %2\n\tv_mov_b32 %1, %2\n\ts_nop 1\n\tv_permlane32_swap_b32 %0, %1"
        : "=&v"(a), "=&v"(b) : "v"(x));
}
#endif

// ---- 64-lane all-VALU reductions, result in every lane ----
__device__ __forceinline__ float wred_add(float x) {
    x += dppmov<0xB1>(x);
    x += dppmov<0x4E>(x);
    x += dppmov<0x141>(x);
    x += dppmov<0x140>(x);
    { float a, b; sswap16(x, a, b); x = a + b; }
    { float a, b; sswap32(x, a, b); x = a + b; }
    return x;
}
__device__ __forceinline__ float wred_max(float x) {
    x = fmaxf(x, dppmov<0xB1>(x));
    x = fmaxf(x, dppmov<0x4E>(x));
    x = fmaxf(x, dppmov<0x141>(x));
    x = fmaxf(x, dppmov<0x140>(x));
    { float a, b; sswap16(x, a, b); x = fmaxf(a, b); }
    { float a, b; sswap32(x, a, b); x = fmaxf(a, b); }
    return x;
}

__device__ __forceinline__ float rdlane(float x, int lane) {
    return __int_as_float(__builtin_amdgcn_readlane(__float_as_int(x), lane));
}
__device__ __forceinline__ float rdfirst(float x) {
    return __int_as_float(__builtin_amdgcn_readfirstlane(__float_as_int(x)));
}

// ================= full-GPU prep =================

// fused: per-event norms (blocks 0..1023) + W row SQUARED norms + hist (1024..1039)
__global__ void prep_kernel(const float* __restrict__ all_ts, const float* __restrict__ W,
                            const float* __restrict__ ch, float* __restrict__ nrm,
                            float* __restrict__ wnsq_g, float* __restrict__ hist_g) {
    const int l = threadIdx.x & 63;
    const int wv = threadIdx.x >> 6;
    const int blk = blockIdx.x;
    if (blk < 1024) {
        const int e = blk * 4 + wv;
        const float4* src = (const float4*)(all_ts + (size_t)e * TS);
        float s = 0.f;
        #pragma unroll
        for (int c = 0; c < 4; ++c) {
            float4 f = src[64 * c + l];
            s = fmaf(f.x, f.x, fmaf(f.y, f.y, fmaf(f.z, f.z, fmaf(f.w, f.w, s))));
        }
        const float tsn = sqrtf(wred_add(s));
        if (l == 0) nrm[e] = tsn;
    } else {
        const int r = (blk - 1024) * 4 + wv;
        const float4* row = (const float4*)(W + (size_t)r * TS);
        float s = 0.f;
        #pragma unroll
        for (int c = 0; c < 4; ++c) {
            float4 f = row[64 * c + l];
            s = fmaf(f.x, f.x, fmaf(f.y, f.y, fmaf(f.z, f.z, fmaf(f.w, f.w, s))));
        }
        const float tot = wred_add(s);
        if (l == 0) wnsq_g[r] = tot;   // squared norm
        if (blk == 1024 && threadIdx.x < NN) hist_g[threadIdx.x] = ch[threadIdx.x];
    }
}

// Gram diagonal-block tiles: Gt[b][i][j] = ts_i . ts_j (within block), j>=i tiles
__global__ void gtile_kernel(const float* __restrict__ ts, float* __restrict__ Gt) {
    const int tj = blockIdx.x, ti = blockIdx.y, b = blockIdx.z;
    if (tj < ti) return;
    __shared__ float As[32][36];
    __shared__ float Bs[32][36];
    const float* base = ts + (size_t)b * BLK * TS;
    const int tid = threadIdx.x;
    const int ty = tid >> 4, tx = tid & 15;
    const int lr = tid >> 3, lc = (tid & 7) << 2;
    float a00 = 0, a01 = 0, a10 = 0, a11 = 0;
    for (int k0 = 0; k0 < TS; k0 += 32) {
        float4 av = *(const float4*)(base + (size_t)(ti * 32 + lr) * TS + k0 + lc);
        float4 bv = *(const float4*)(base + (size_t)(tj * 32 + lr) * TS + k0 + lc);
        __syncthreads();
        *(float4*)&As[lr][lc] = av;
        *(float4*)&Bs[lr][lc] = bv;
        __syncthreads();
        #pragma unroll
        for (int kk = 0; kk < 32; kk += 4) {
            const float4 x0 = *(const float4*)&As[2 * ty][kk];
            const float4 x1 = *(const float4*)&As[2 * ty + 1][kk];
            const float4 y0 = *(const float4*)&Bs[2 * tx][kk];
            const float4 y1 = *(const float4*)&Bs[2 * tx + 1][kk];
            a00 = fmaf(x0.x, y0.x, fmaf(x0.y, y0.y, fmaf(x0.z, y0.z, fmaf(x0.w, y0.w, a00))));
            a01 = fmaf(x0.x, y1.x, fmaf(x0.y, y1.y, fmaf(x0.z, y1.z, fmaf(x0.w, y1.w, a01))));
            a10 = fmaf(x1.x, y0.x, fmaf(x1.y, y0.y, fmaf(x1.z, y0.z, fmaf(x1.w, y0.w, a10))));
            a11 = fmaf(x1.x, y1.x, fmaf(x1.y, y1.y, fmaf(x1.z, y1.z, fmaf(x1.w, y1.w, a11))));
        }
    }
    float* g = Gt + (size_t)b * BLK * BLK;
    const int i0 = ti * 32 + 2 * ty, j0 = tj * 32 + 2 * tx;
    g[(size_t)i0 * BLK + j0]           = a00;
    g[(size_t)i0 * BLK + j0 + 1]       = a01;
    g[(size_t)(i0 + 1) * BLK + j0]     = a10;
    g[(size_t)(i0 + 1) * BLK + j0 + 1] = a11;
}

// D refresh; stores TRANSPOSED + XOR-SWIZZLED: D_g[f*64 + (n ^ (f&31))] = W[n].ts_f
__global__ void dgemm_kernel(const float* __restrict__ Wc, const float* __restrict__ tsb,
                             float* __restrict__ D_g) {
    const int tj = blockIdx.x, ti = blockIdx.y;
    __shared__ float As[32][36];
    __shared__ float Bs[32][36];
    const int tid = threadIdx.x;
    const int ty = tid >> 4, tx = tid & 15;
    const int lr = tid >> 3, lc = (tid & 7) << 2;
    float a00 = 0, a01 = 0, a10 = 0, a11 = 0;
    for (int k0 = 0; k0 < TS; k0 += 32) {
        float4 av = *(const float4*)(Wc + (size_t)(ti * 32 + lr) * TS + k0 + lc);
        float4 bv = *(const float4*)(tsb + (size_t)(tj * 32 + lr) * TS + k0 + lc);
        __syncthreads();
        *(float4*)&As[lr][lc] = av;
        *(float4*)&Bs[lr][lc] = bv;
        __syncthreads();
        #pragma unroll
        for (int kk = 0; kk < 32; kk += 4) {
            const float4 x0 = *(const float4*)&As[2 * ty][kk];
            const float4 x1 = *(const float4*)&As[2 * ty + 1][kk];
            const float4 y0 = *(const float4*)&Bs[2 * tx][kk];
            const float4 y1 = *(const float4*)&Bs[2 * tx + 1][kk];
            a00 = fmaf(x0.x, y0.x, fmaf(x0.y, y0.y, fmaf(x0.z, y0.z, fmaf(x0.w, y0.w, a00))));
            a01 = fmaf(x0.x, y1.x, fmaf(x0.y, y1.y, fmaf(x0.z, y1.z, fmaf(x0.w, y1.w, a01))));
            a10 = fmaf(x1.x, y0.x, fmaf(x1.y, y0.y, fmaf(x1.z, y0.z, fmaf(x1.w, y0.w, a10))));
            a11 = fmaf(x1.x, y1.x, fmaf(x1.y, y1.y, fmaf(x1.z, y1.z, fmaf(x1.w, y1.w, a11))));
        }
    }
    const int n0 = ti * 32 + 2 * ty, f0 = tj * 32 + 2 * tx;
    D_g[(size_t)f0 * 64       + ((n0)     ^ (f0 & 31))]       = a00;
    D_g[(size_t)(f0 + 1) * 64 + ((n0)     ^ ((f0 + 1) & 31))] = a01;
    D_g[(size_t)f0 * 64       + ((n0 + 1) ^ (f0 & 31))]       = a10;
    D_g[(size_t)(f0 + 1) * 64 + ((n0 + 1) ^ ((f0 + 1) & 31))] = a11;
}

// W rebuild: LDS-staged log replay (no dependent global loads in the scan loop)
__global__ void rebuild_kernel(float* __restrict__ Wc, const float* __restrict__ ts,
                               const int* __restrict__ win, const float* __restrict__ coef_g,
                               const float* __restrict__ nrm, int b) {
    __shared__ int   wl[BLK];
    __shared__ float cl[BLK];
    __shared__ float rl[BLK];
    const int n = blockIdx.x;
    const int d = blockIdx.y * 256 + threadIdx.x;
    const int e0 = b * BLK;
    for (int i = threadIdx.x; i < BLK; i += 256) {
        wl[i] = win[e0 + i];
        cl[i] = coef_g[e0 + i];
        rl[i] = __builtin_amdgcn_rcpf(nrm[e0 + i]);
    }
    __syncthreads();
    float wv = Wc[(size_t)n * TS + d];
    #pragma unroll 4
    for (int i = 0; i < BLK; ++i) {
        if (wl[i] == n) {
            const float tn = ts[(size_t)(e0 + i) * TS + d] * rl[i];
            wv = fmaf(cl[i], tn - wv, wv);
        }
    }
    Wc[(size_t)n * TS + d] = wv;
}

// ================= single-wave sequential core (speculative) =================
// LDS: D[n][f] at word f*64 + (n ^ (f&31)). Wrapped (dead) columns absorb
// out-of-range rank-1 writes; columns <= current event are never read again.

#define ITER(I, GC, TSC, TSO)                                                   \
    {                                                                           \
        /* stale read of next column (pre this event's RMW, by design) */       \
        const unsigned c1 = (unsigned)((I) + 1) & 511u;                         \
        const float dv_nx = Dl[(c1 << 6) + ((unsigned)l ^ (c1 & 31u))];         \
        const float rtn = rtncur;                                               \
        float rg[8];                                                            \
        _Pragma("unroll")                                                       \
        for (int k = 0; k < 8; ++k) rg[k] = rtn * GC[k];                        \
        /* ---- on-path: fix lane mprev, resolve event I ---- */                \
        const float dvp   = rdlane(dvpre_carry, mprev);                         \
        const float dvfix = fmaf(coef_prev, rgsd_prev - dvp, dvp);              \
        const float bfix  = dvfix * rtn * rdlane(rwn, mprev);                   \
        const float sfix  = rdlane(gain, mprev) * bfix;                         \
        const float excl  = (m1 == (1ull << mprev)) ? v2 : v1;                  \
        const float smax  = fmaxf(excl, sfix);                                  \
        const float scorr = (l == mprev) ? sfix : s_carry;                      \
        const unsigned long long bal = __ballot(scorr == smax);                 \
        const int m = (int)(__ffsll(bal) - 1);                                  \
        const float Dm   = (m == mprev) ? dvfix : rdlane(dvpre_carry, m);       \
        const float betw = (m == mprev) ? bfix  : rdlane(beta_carry, m);        \
        const float coef = rdlane(alpha, m) * betw;                             \
        if (l == 0) { out[e0 + (I)] = m; coef_g[e0 + (I)] = coef; }             \
        /* ---- rank-1 LDS update of row m, all later cols ---- */              \
        {                                                                       \
            const unsigned f0 = (unsigned)((I) + 1 + l) & 511u;                 \
            const unsigned xr = ((unsigned)(m ^ (int)(f0 & 31u))) << 2;         \
            _Pragma("unroll")                                                   \
            for (int k = 0; k < 8; ++k) {                                       \
                const unsigned fk = ((f0 + 64u * (unsigned)k) & 511u) << 8;     \
                float* p = (float*)((char*)Dl + (fk + xr));                     \
                const float d0 = *p;                                            \
                *p = fmaf(coef, rg[k] - d0, d0);                                \
            }                                                                   \
        }                                                                       \
        /* ---- winner-state update (uniform values + per-lane select) ---- */  \
        const float wsq_m = rdlane(wnsq, m);                                    \
        const float om = 1.0f - coef;                                           \
        const float bwt = Dm * rtn;                                             \
        const float wsq_new = fmaf(om * om, wsq_m,                              \
                                   fmaf(2.0f * coef * om, bwt, coef * coef));   \
        const float rwn_new = __builtin_amdgcn_rsqf(wsq_new);                   \
        const float hll_new = rdlane(hll, m) + 1.0f;                            \
        const float alp_new = 0.01f * __builtin_amdgcn_rcpf(fmaf(hll_new, 1.0f / 20000.0f, 1.0f)); \
        if (l == m) { wnsq = wsq_new; rwn = rwn_new; hll = hll_new; alpha = alp_new; } \
        hs += 1.0f;                                                             \
        gain = __expf(0.25f - 16.0f * hll * __builtin_amdgcn_rcpf(hs));         \
        /* ---- speculative scores for event I+1 (exact except lane m) ---- */  \
        const float rtn_nx = __builtin_amdgcn_rcpf(TSO);                        \
        const float bst = dv_nx * rtn_nx * rwn;                                 \
        const float sst = gain * bst;                                           \
        v1 = wred_max(sst);                                                     \
        m1 = __ballot(sst == v1);                                               \
        v2 = wred_max((sst == v1) ? -FLT_MAX : sst);                            \
        s_carry = sst; beta_carry = bst; dvpre_carry = dv_nx;                   \
        mprev = m; coef_prev = coef;                                            \
        rgsd_prev = rdfirst(rg[0]);          /* = rtn * G(I, I+1), lane 0 */    \
        rtncur = rtn_nx;                                                        \
        /* ---- refills (2-deep parity) ---- */                                 \
        TSC = nrm[e0 + (I) + 2];                                                \
        {                                                                       \
            const float* gr = Gt_b + 512 * ((I) + 2) + ((I) + 3 + l);           \
            _Pragma("unroll")                                                   \
            for (int k = 0; k < 8; ++k) GC[k] = gr[64 * k];                     \
        }                                                                       \
    }

__launch_bounds__(512, 1)
__global__ void seq_kernel(const float* __restrict__ D_g, const float* __restrict__ Gt_b,
                           const float* __restrict__ nrm, float* __restrict__ wnsq_g,
                           float* __restrict__ hist_g, int* __restrict__ out,
                           float* __restrict__ coef_g, int b)
{
    __shared__ float Dl[NN * BLK];   // 128 KB
    const int t = threadIdx.x;

    // cooperative fill (D_g already transposed+swizzled): linear float4 copy
    {
        const float4* Dg4 = (const float4*)D_g;
        float4* Dl4 = (float4*)Dl;
        #pragma unroll
        for (int c = 0; c < 16; ++c) Dl4[c * 512 + t] = Dg4[c * 512 + t];
    }
    __syncthreads();
    if (t >= 64) return;            // wave 0 runs the scan alone
    const int l = t;

    const int e0 = b * BLK;
    float wnsq = wnsq_g[l];
    float hll  = hist_g[l];
    float rwn  = __builtin_amdgcn_rsqf(wnsq);
    float alpha = 0.01f * __builtin_amdgcn_rcpf(fmaf(hll, 1.0f / 20000.0f, 1.0f));
    float hs = 64.0f + (float)e0;
    float gain = __expf(0.25f - 16.0f * hll * __builtin_amdgcn_rcpf(hs));

    // spec for event 0 (exact; no pending fix: coef_prev = 0)
    float rtncur = __builtin_amdgcn_rcpf(nrm[e0]);
    float dvpre_carry = Dl[l];                     // column 0
    float beta_carry = dvpre_carry * rtncur * rwn;
    float s_carry = gain * beta_carry;
    float v1 = wred_max(s_carry);
    unsigned long long m1 = __ballot(s_carry == v1);
    float v2 = wred_max((s_carry == v1) ? -FLT_MAX : s_carry);
    int mprev = 0;
    float coef_prev = 0.0f, rgsd_prev = 0.0f;

    // parity prefetch: norms + G rows 0/1
    float tsA = nrm[e0], tsB = nrm[e0 + 1];
    float gA[8], gB[8];
    {
        const float* gr = Gt_b + (1 + l);
        #pragma unroll
        for (int k = 0; k < 8; ++k) gA[k] = gr[64 * k];
    }
    {
        const float* gr = Gt_b + 512 + (2 + l);
        #pragma unroll
        for (int k = 0; k < 8; ++k) gB[k] = gr[64 * k];
    }

    #pragma unroll 1
    for (int i = 0; i < BLK; i += 2) {
        ITER(i,     gA, tsA, tsB);
        ITER(i + 1, gB, tsB, tsA);
    }

    wnsq_g[l] = wnsq;
    hist_g[l] = hll;
}

// ================= launch =================
// ws layout (floats); GT first so tail over-reads land in our own arrays.
#define GT_OFF    0                          // 8 * 512 * 512 = 2097152
#define NRM_OFF   2097152                    // 4096
#define WN_OFF    2101248                    // 64 (squared norms)
#define HIST_OFF  2101312                    // 64
#define COEF_OFF  2101376                    // 4096
#define D_OFF     2105472                    // 32768
#define W_OFF     2138240                    // 65536 -> total 2203776 floats (8.8 MB)

extern "C" void kernel_launch(void* const* d_in, const int* in_sizes, int n_in,
                              void* d_out, int out_size, void* d_ws, size_t ws_size,
                              hipStream_t stream) {
    const float* all_ts   = (const float*)d_in[0];
    const float* W        = (const float*)d_in[1];
    const float* cumhisto = (const float*)d_in[2];
    int* out = (int*)d_out;
    float* ws = (float*)d_ws;

    float* Gt     = ws + GT_OFF;
    float* nrm    = ws + NRM_OFF;
    float* wnsq_g = ws + WN_OFF;
    float* hist_g = ws + HIST_OFF;
    float* coef_g = ws + COEF_OFF;
    float* D_g    = ws + D_OFF;
    float* W_cur  = ws + W_OFF;

    hipMemcpyAsync(W_cur, W, (size_t)NN * TS * sizeof(float),
                   hipMemcpyDeviceToDevice, stream);
    prep_kernel<<<1040, 256, 0, stream>>>(all_ts, W, cumhisto, nrm, wnsq_g, hist_g);
    gtile_kernel<<<dim3(16, 16, NBLK), 256, 0, stream>>>(all_ts, Gt);

    for (int b = 0; b < NBLK; ++b) {
        dgemm_kernel<<<dim3(16, 2), 256, 0, stream>>>(
            W_cur, all_ts + (size_t)b * BLK * TS, D_g);
        seq_kernel<<<1, 512, 0, stream>>>(
            D_g, Gt + (size_t)b * BLK * BLK, nrm, wnsq_g, hist_g, out, coef_g, b);
        if (b < NBLK - 1)
            rebuild_kernel<<<dim3(NN, 4), 256, 0, stream>>>(
                W_cur, all_ts, out, coef_g, nrm, b);
    }
}

// Round 8
// 2909.290 us; speedup vs baseline: 1.1059x; 1.1059x over previous
//
#include <hip/hip_runtime.h>
#include <math.h>
#include <float.h>

#define N_EVENTS 4096
#define TS 1024
#define NN 64
#define BLK 512          // events per sequential block
#define NBLK (N_EVENTS / BLK)

typedef int v2i __attribute__((ext_vector_type(2)));

// ---- DPP permute ----
template<int CTRL>
__device__ __forceinline__ float dppmov(float x) {
    return __int_as_float(__builtin_amdgcn_mov_dpp(__float_as_int(x), CTRL, 0xF, 0xF, true));
}
// 0xB1 quad xor1, 0x4E quad xor2, 0x141 row_half_mirror, 0x140 row_mirror

// ---- gfx950 permlane swaps (self-swap helpers for full-wave reduce) ----
#if __has_builtin(__builtin_amdgcn_permlane16_swap) && __has_builtin(__builtin_amdgcn_permlane32_swap)
__device__ __forceinline__ void sswap16(float x, float& a, float& b) {
    v2i r = __builtin_amdgcn_permlane16_swap(__float_as_int(x), __float_as_int(x), false, false);
    a = __int_as_float(r[0]); b = __int_as_float(r[1]);
}
__device__ __forceinline__ void sswap32(float x, float& a, float& b) {
    v2i r = __builtin_amdgcn_permlane32_swap(__float_as_int(x), __float_as_int(x), false, false);
    a = __int_as_float(r[0]); b = __int_as_float(r[1]);
}
#else
__device__ __forceinline__ void sswap16(float x, float& a, float& b) {
    asm("v_mov_b32 %0, %2\n\tv_mov_b32 %1, %2\n\ts_nop 1\n\tv_permlane16_swap_b32 %0, %1"
        : "=&v"(a), "=&v"(b) : "v"(x));
}
__device__ __forceinline__ void sswap32(float x, float& a, float& b) {
    asm("v_mov_b32 %0, %2\n\tv_mov_b32 %1, %2\n\ts_nop 1\n\tv_permlane32_swap_b32 %0, %1"
        : "=&v"(a), "=&v"(b) : "v"(x));
}
#endif

// ---- 64-lane all-VALU reductions, result in every lane ----
__device__ __forceinline__ float wred_add(float x) {
    x += dppmov<0xB1>(x);
    x += dppmov<0x4E>(x);
    x += dppmov<0x141>(x);
    x += dppmov<0x140>(x);
    { float a, b; sswap16(x, a, b); x = a + b; }
    { float a, b; sswap32(x, a, b); x = a + b; }
    return x;
}
__device__ __forceinline__ float wred_max(float x) {
    x = fmaxf(x, dppmov<0xB1>(x));
    x = fmaxf(x, dppmov<0x4E>(x));
    x = fmaxf(x, dppmov<0x141>(x));
    x = fmaxf(x, dppmov<0x140>(x));
    { float a, b; sswap16(x, a, b); x = fmaxf(a, b); }
    { float a, b; sswap32(x, a, b); x = fmaxf(a, b); }
    return x;
}

__device__ __forceinline__ float rdlane(float x, int lane) {
    return __int_as_float(__builtin_amdgcn_readlane(__float_as_int(x), lane));
}

// ================= full-GPU prep =================

// fused: per-event norms (blocks 0..1023) + W row SQUARED norms + hist (1024..1039)
__global__ void prep_kernel(const float* __restrict__ all_ts, const float* __restrict__ W,
                            const float* __restrict__ ch, float* __restrict__ nrm,
                            float* __restrict__ wnsq_g, float* __restrict__ hist_g) {
    const int l = threadIdx.x & 63;
    const int wv = threadIdx.x >> 6;
    const int blk = blockIdx.x;
    if (blk < 1024) {
        const int e = blk * 4 + wv;
        const float4* src = (const float4*)(all_ts + (size_t)e * TS);
        float s = 0.f;
        #pragma unroll
        for (int c = 0; c < 4; ++c) {
            float4 f = src[64 * c + l];
            s = fmaf(f.x, f.x, fmaf(f.y, f.y, fmaf(f.z, f.z, fmaf(f.w, f.w, s))));
        }
        const float tsn = sqrtf(wred_add(s));
        if (l == 0) nrm[e] = tsn;
    } else {
        const int r = (blk - 1024) * 4 + wv;
        const float4* row = (const float4*)(W + (size_t)r * TS);
        float s = 0.f;
        #pragma unroll
        for (int c = 0; c < 4; ++c) {
            float4 f = row[64 * c + l];
            s = fmaf(f.x, f.x, fmaf(f.y, f.y, fmaf(f.z, f.z, fmaf(f.w, f.w, s))));
        }
        const float tot = wred_add(s);
        if (l == 0) wnsq_g[r] = tot;   // squared norm
        if (blk == 1024 && threadIdx.x < NN) hist_g[threadIdx.x] = ch[threadIdx.x];
    }
}

// Gram diagonal-block tiles: Gt[b][i][j] = ts_i . ts_j (within block), j>=i tiles
__global__ void gtile_kernel(const float* __restrict__ ts, float* __restrict__ Gt) {
    const int tj = blockIdx.x, ti = blockIdx.y, b = blockIdx.z;
    if (tj < ti) return;
    __shared__ float As[32][36];
    __shared__ float Bs[32][36];
    const float* base = ts + (size_t)b * BLK * TS;
    const int tid = threadIdx.x;
    const int ty = tid >> 4, tx = tid & 15;
    const int lr = tid >> 3, lc = (tid & 7) << 2;
    float a00 = 0, a01 = 0, a10 = 0, a11 = 0;
    for (int k0 = 0; k0 < TS; k0 += 32) {
        float4 av = *(const float4*)(base + (size_t)(ti * 32 + lr) * TS + k0 + lc);
        float4 bv = *(const float4*)(base + (size_t)(tj * 32 + lr) * TS + k0 + lc);
        __syncthreads();
        *(float4*)&As[lr][lc] = av;
        *(float4*)&Bs[lr][lc] = bv;
        __syncthreads();
        #pragma unroll
        for (int kk = 0; kk < 32; kk += 4) {
            const float4 x0 = *(const float4*)&As[2 * ty][kk];
            const float4 x1 = *(const float4*)&As[2 * ty + 1][kk];
            const float4 y0 = *(const float4*)&Bs[2 * tx][kk];
            const float4 y1 = *(const float4*)&Bs[2 * tx + 1][kk];
            a00 = fmaf(x0.x, y0.x, fmaf(x0.y, y0.y, fmaf(x0.z, y0.z, fmaf(x0.w, y0.w, a00))));
            a01 = fmaf(x0.x, y1.x, fmaf(x0.y, y1.y, fmaf(x0.z, y1.z, fmaf(x0.w, y1.w, a01))));
            a10 = fmaf(x1.x, y0.x, fmaf(x1.y, y0.y, fmaf(x1.z, y0.z, fmaf(x1.w, y0.w, a10))));
            a11 = fmaf(x1.x, y1.x, fmaf(x1.y, y1.y, fmaf(x1.z, y1.z, fmaf(x1.w, y1.w, a11))));
        }
    }
    float* g = Gt + (size_t)b * BLK * BLK;
    const int i0 = ti * 32 + 2 * ty, j0 = tj * 32 + 2 * tx;
    g[(size_t)i0 * BLK + j0]           = a00;
    g[(size_t)i0 * BLK + j0 + 1]       = a01;
    g[(size_t)(i0 + 1) * BLK + j0]     = a10;
    g[(size_t)(i0 + 1) * BLK + j0 + 1] = a11;
}

// D refresh; stores TRANSPOSED + XOR-SWIZZLED: D_g[f*64 + (n ^ (f&31))] = W[n].ts_f
__global__ void dgemm_kernel(const float* __restrict__ Wc, const float* __restrict__ tsb,
                             float* __restrict__ D_g) {
    const int tj = blockIdx.x, ti = blockIdx.y;
    __shared__ float As[32][36];
    __shared__ float Bs[32][36];
    const int tid = threadIdx.x;
    const int ty = tid >> 4, tx = tid & 15;
    const int lr = tid >> 3, lc = (tid & 7) << 2;
    float a00 = 0, a01 = 0, a10 = 0, a11 = 0;
    for (int k0 = 0; k0 < TS; k0 += 32) {
        float4 av = *(const float4*)(Wc + (size_t)(ti * 32 + lr) * TS + k0 + lc);
        float4 bv = *(const float4*)(tsb + (size_t)(tj * 32 + lr) * TS + k0 + lc);
        __syncthreads();
        *(float4*)&As[lr][lc] = av;
        *(float4*)&Bs[lr][lc] = bv;
        __syncthreads();
        #pragma unroll
        for (int kk = 0; kk < 32; kk += 4) {
            const float4 x0 = *(const float4*)&As[2 * ty][kk];
            const float4 x1 = *(const float4*)&As[2 * ty + 1][kk];
            const float4 y0 = *(const float4*)&Bs[2 * tx][kk];
            const float4 y1 = *(const float4*)&Bs[2 * tx + 1][kk];
            a00 = fmaf(x0.x, y0.x, fmaf(x0.y, y0.y, fmaf(x0.z, y0.z, fmaf(x0.w, y0.w, a00))));
            a01 = fmaf(x0.x, y1.x, fmaf(x0.y, y1.y, fmaf(x0.z, y1.z, fmaf(x0.w, y1.w, a01))));
            a10 = fmaf(x1.x, y0.x, fmaf(x1.y, y0.y, fmaf(x1.z, y0.z, fmaf(x1.w, y0.w, a10))));
            a11 = fmaf(x1.x, y1.x, fmaf(x1.y, y1.y, fmaf(x1.z, y1.z, fmaf(x1.w, y1.w, a11))));
        }
    }
    const int n0 = ti * 32 + 2 * ty, f0 = tj * 32 + 2 * tx;
    D_g[(size_t)f0 * 64       + ((n0)     ^ (f0 & 31))]       = a00;
    D_g[(size_t)(f0 + 1) * 64 + ((n0)     ^ ((f0 + 1) & 31))] = a01;
    D_g[(size_t)f0 * 64       + ((n0 + 1) ^ (f0 & 31))]       = a10;
    D_g[(size_t)(f0 + 1) * 64 + ((n0 + 1) ^ ((f0 + 1) & 31))] = a11;
}

// W rebuild: LDS-staged log replay
__global__ void rebuild_kernel(float* __restrict__ Wc, const float* __restrict__ ts,
                               const int* __restrict__ win, const float* __restrict__ coef_g,
                               const float* __restrict__ nrm, int b) {
    __shared__ int   wl[BLK];
    __shared__ float cl[BLK];
    __shared__ float rl[BLK];
    const int n = blockIdx.x;
    const int d = blockIdx.y * 256 + threadIdx.x;
    const int e0 = b * BLK;
    for (int i = threadIdx.x; i < BLK; i += 256) {
        wl[i] = win[e0 + i];
        cl[i] = coef_g[e0 + i];
        rl[i] = __builtin_amdgcn_rcpf(nrm[e0 + i]);
    }
    __syncthreads();
    float wv = Wc[(size_t)n * TS + d];
    #pragma unroll 4
    for (int i = 0; i < BLK; ++i) {
        if (wl[i] == n) {
            const float tn = ts[(size_t)(e0 + i) * TS + d] * rl[i];
            wv = fmaf(cl[i], tn - wv, wv);
        }
    }
    Wc[(size_t)n * TS + d] = wv;
}

// ========== multi-wave speculative sequential core ==========
// LDS: D[n][f] at word f*64 + (n ^ (f&31)); 256 dump slots after.
// Thread t owns columns t and t+256: the ONLY writer of those columns.
// Column k+1 is stale-read in step k; its owner skips event k's update
// (the in-register fix at resolve of event k+1 supplies it). Hence the
// single read and all writes in a step are disjoint -> 1 barrier/step.
#define DUMPW (NN * BLK)

#define ITER(I, GP0, GP1, GDP, TSC, TSO)                                        \
    {                                                                           \
        /* stale read of next column (state: events <= I-1, by design) */       \
        const unsigned cc = (unsigned)((I) + 1) & 511u;                         \
        const float dv_nx = Dl[(cc << 6) + ((unsigned)l ^ (cc & 31u))];         \
        const float rtn = rtncur;                                               \
        /* ---- resolve event I (VALU-only; all waves redundantly) ---- */      \
        const float dvp   = rdlane(dvpre_carry, mprev);                         \
        const float dvfix = fmaf(coef_prev, rgsd_prev - dvp, dvp);              \
        const float bfix  = dvfix * rtn * rdlane(rwn, mprev);                   \
        const float sfix  = rdlane(gain, mprev) * bfix;                         \
        const float excl  = (m1 == (1ull << mprev)) ? v2 : v1;                  \
        const float smax  = fmaxf(excl, sfix);                                  \
        const float scorr = (l == mprev) ? sfix : s_carry;                      \
        const unsigned long long bal = __ballot(scorr == smax);                 \
        const int m = (int)(__ffsll(bal) - 1);                                  \
        const float Dm   = (m == mprev) ? dvfix : rdlane(dvpre_carry, m);       \
        const float betw = (m == mprev) ? bfix  : rdlane(beta_carry, m);        \
        const float coef = rdlane(alpha, m) * betw;                             \
        if (t == 0) { out[e0 + (I)] = m; coef_g[e0 + (I)] = coef; }             \
        /* ---- rank-1 update: thread t -> its two columns (or dump) ---- */    \
        {                                                                       \
            const int mx = m ^ (t & 31);                                        \
            const int a0 = (t >= (I) + 2) ? (t * 64 + mx) : (DUMPW + t);        \
            const int a1 = ((I) <= t + 254) ? ((t + 256) * 64 + mx) : (DUMPW + t); \
            const float u0 = Dl[a0];                                            \
            const float u1 = Dl[a1];                                            \
            Dl[a0] = fmaf(coef, rtn * (GP0) - u0, u0);                          \
            Dl[a1] = fmaf(coef, rtn * (GP1) - u1, u1);                          \
        }                                                                       \
        /* ---- winner-state update ---- */                                     \
        const float wsq_m = rdlane(wnsq, m);                                    \
        const float om = 1.0f - coef;                                           \
        const float bwt = Dm * rtn;                                             \
        const float wsq_new = fmaf(om * om, wsq_m,                              \
                                   fmaf(2.0f * coef * om, bwt, coef * coef));   \
        const float rwn_new = __builtin_amdgcn_rsqf(wsq_new);                   \
        const float hll_new = rdlane(hll, m) + 1.0f;                            \
        const float alp_new = 0.01f * __builtin_amdgcn_rcpf(fmaf(hll_new, 1.0f / 20000.0f, 1.0f)); \
        if (l == m) { wnsq = wsq_new; rwn = rwn_new; hll = hll_new; alpha = alp_new; } \
        hs += 1.0f;                                                             \
        gain = __expf(0.25f - 16.0f * hll * __builtin_amdgcn_rcpf(hs));         \
        /* ---- speculative scores for event I+1 (exact except lane m) ---- */  \
        const float rtn_nx = __builtin_amdgcn_rcpf(TSO);                        \
        const float bst = dv_nx * rtn_nx * rwn;                                 \
        const float sst = gain * bst;                                           \
        v1 = wred_max(sst);                                                     \
        m1 = __ballot(sst == v1);                                               \
        v2 = wred_max((sst == v1) ? -FLT_MAX : sst);                            \
        s_carry = sst; beta_carry = bst; dvpre_carry = dv_nx;                   \
        mprev = m; coef_prev = coef;                                            \
        rgsd_prev = rtn * (GDP);            /* rtn_I * G(I, I+1), uniform */    \
        rtncur = rtn_nx;                                                        \
        /* ---- refills for step I+2 (this parity) ---- */                      \
        TSC = nrm[e0 + (I) + 2];                                                \
        GP0 = Gt_b[512 * ((I) + 2) + t];                                        \
        GP1 = Gt_b[512 * ((I) + 2) + t + 256];                                  \
        GDP = Gt_b[512 * ((I) + 2) + (I) + 3];                                  \
        __syncthreads();                                                        \
    }

__launch_bounds__(256, 1)
__global__ void seq_kernel(const float* __restrict__ D_g, const float* __restrict__ Gt_b,
                           const float* __restrict__ nrm, float* __restrict__ wnsq_g,
                           float* __restrict__ hist_g, int* __restrict__ out,
                           float* __restrict__ coef_g, int b)
{
    __shared__ float Dl[NN * BLK + 256];   // 128 KB + dump
    const int t = threadIdx.x;             // 256 threads = 4 waves
    const int l = t & 63;

    // fill D (already transposed+swizzled): linear float4 copy
    {
        const float4* Dg4 = (const float4*)D_g;
        float4* Dl4 = (float4*)Dl;
        #pragma unroll
        for (int c = 0; c < 32; ++c) Dl4[c * 256 + t] = Dg4[c * 256 + t];
    }

    const int e0 = b * BLK;
    // per-lane neuron state, replicated identically in all 4 waves
    float wnsq = wnsq_g[l];
    float hll  = hist_g[l];
    float rwn  = __builtin_amdgcn_rsqf(wnsq);
    float alpha = 0.01f * __builtin_amdgcn_rcpf(fmaf(hll, 1.0f / 20000.0f, 1.0f));
    float hs = 64.0f + (float)e0;
    float gain = __expf(0.25f - 16.0f * hll * __builtin_amdgcn_rcpf(hs));

    __syncthreads();

    // spec for event 0 (exact; pending fix disabled via coef_prev = 0)
    float rtncur = __builtin_amdgcn_rcpf(nrm[e0]);
    float dvpre_carry = Dl[l];                     // column 0, row l
    float beta_carry = dvpre_carry * rtncur * rwn;
    float s_carry = gain * beta_carry;
    float v1 = wred_max(s_carry);
    unsigned long long m1 = __ballot(s_carry == v1);
    float v2 = wred_max((s_carry == v1) ? -FLT_MAX : s_carry);
    int mprev = 0;
    float coef_prev = 0.0f, rgsd_prev = 0.0f;

    // parity prefetch: norms + G rows 0/1 (per-thread cols t, t+256; diag)
    float tsA = nrm[e0], tsB = nrm[e0 + 1];
    float gA0 = Gt_b[t],        gA1 = Gt_b[t + 256],        gdA = Gt_b[1];
    float gB0 = Gt_b[512 + t],  gB1 = Gt_b[512 + t + 256],  gdB = Gt_b[512 + 2];

    #pragma unroll 1
    for (int i = 0; i < BLK; i += 2) {
        ITER(i,     gA0, gA1, gdA, tsA, tsB);
        ITER(i + 1, gB0, gB1, gdB, tsB, tsA);
    }

    if (t < NN) { wnsq_g[l] = wnsq; hist_g[l] = hll; }
}

// ================= launch =================
// ws layout (floats); GT first so tail over-reads land in our own arrays.
#define GT_OFF    0                          // 8 * 512 * 512 = 2097152
#define NRM_OFF   2097152                    // 4096
#define WN_OFF    2101248                    // 64 (squared norms)
#define HIST_OFF  2101312                    // 64
#define COEF_OFF  2101376                    // 4096
#define D_OFF     2105472                    // 32768
#define W_OFF     2138240                    // 65536 -> total 2203776 floats (8.8 MB)

extern "C" void kernel_launch(void* const* d_in, const int* in_sizes, int n_in,
                              void* d_out, int out_size, void* d_ws, size_t ws_size,
                              hipStream_t stream) {
    const float* all_ts   = (const float*)d_in[0];
    const float* W        = (const float*)d_in[1];
    const float* cumhisto = (const float*)d_in[2];
    int* out = (int*)d_out;
    float* ws = (float*)d_ws;

    float* Gt     = ws + GT_OFF;
    float* nrm    = ws + NRM_OFF;
    float* wnsq_g = ws + WN_OFF;
    float* hist_g = ws + HIST_OFF;
    float* coef_g = ws + COEF_OFF;
    float* D_g    = ws + D_OFF;
    float* W_cur  = ws + W_OFF;

    hipMemcpyAsync(W_cur, W, (size_t)NN * TS * sizeof(float),
                   hipMemcpyDeviceToDevice, stream);
    prep_kernel<<<1040, 256, 0, stream>>>(all_ts, W, cumhisto, nrm, wnsq_g, hist_g);
    gtile_kernel<<<dim3(16, 16, NBLK), 256, 0, stream>>>(all_ts, Gt);

    for (int b = 0; b < NBLK; ++b) {
        dgemm_kernel<<<dim3(16, 2), 256, 0, stream>>>(
            W_cur, all_ts + (size_t)b * BLK * TS, D_g);
        seq_kernel<<<1, 256, 0, stream>>>(
            D_g, Gt + (size_t)b * BLK * BLK, nrm, wnsq_g, hist_g, out, coef_g, b);
        if (b < NBLK - 1)
            rebuild_kernel<<<dim3(NN, 4), 256, 0, stream>>>(
                W_cur, all_ts, out, coef_g, nrm, b);
    }
}